// Round 6
// baseline (23843.268 us; speedup 1.0000x reference)
//
#include <hip/hip_runtime.h>
#include <math.h>
#include <stdint.h>

#define T_STEPS 64
#define A_DIM   16
#define SEQ     1024      // T*A
#define HE      256       // encoder hidden per direction
#define DH      512       // decoder hidden
#define GE      1024      // 4*HE
#define GD      2048      // 4*DH

typedef _Float16 h2_t __attribute__((ext_vector_type(2)));

__device__ __forceinline__ float sigf(float x) { return 1.f / (1.f + __expf(-x)); }
// tanh via exp2-based __expf; args here are bounded (|x| < ~4) so no overflow path.
__device__ __forceinline__ float tanh_fast(float x) {
    float e = __expf(-2.f * x);
    return (1.f - e) / (1.f + e);
}

__device__ __forceinline__ float fdot2f(h2_t a, h2_t b, float c) {
#if defined(__has_builtin) && __has_builtin(__builtin_amdgcn_fdot2)
    return __builtin_amdgcn_fdot2(a, b, c, false);
#else
    return c + (float)a.x * (float)b.x + (float)a.y * (float)b.y;
#endif
}

__device__ __forceinline__ uint32_t pkf16(float a, float b) {
    unsigned short x = __builtin_bit_cast(unsigned short, (_Float16)a);
    unsigned short y = __builtin_bit_cast(unsigned short, (_Float16)b);
    return (uint32_t)x | ((uint32_t)y << 16);
}

// readlane -> wave-uniform h pair (compiler keeps it in an SGPR and folds it
// into v_dot2's VOP3P scalar slot; no inline asm so the scheduler is free)
__device__ __forceinline__ h2_t hlane(uint32_t hreg, int l) {
    return __builtin_bit_cast(h2_t, (uint32_t)__builtin_amdgcn_readlane((int)hreg, l));
}

// Agent-scope self-validating comm words (decoder only). Lesson r1/r2:
// cross-CU exchange must use the L3 coherence point; no fast path exists.
__device__ __forceinline__ float poll_comm(const float* p) {
    float v;
    do {
        v = __hip_atomic_load(p, __ATOMIC_RELAXED, __HIP_MEMORY_SCOPE_AGENT);
    } while (v == 0.f);
    return v - 4.0f;
}

__device__ __forceinline__ void post_comm(float* p, float h) {
    __hip_atomic_store(p, h + 4.0f, __ATOMIC_RELAXED, __HIP_MEMORY_SCOPE_AGENT);
}

// ---------------------------------------------------------------------------
// Embedding / decoder-input assembly
// ---------------------------------------------------------------------------
__global__ void k_embed(const int* __restrict__ lattice, const int* __restrict__ inputs,
                        const int* __restrict__ gold, const int* __restrict__ sos,
                        const float* __restrict__ lat_emb, const float* __restrict__ in_emb,
                        float* __restrict__ x, float* __restrict__ decin)
{
    int idx = blockIdx.x * 256 + threadIdx.x;
    if (idx < SEQ * 256) {
        int row = idx >> 8, e = idx & 255;
        int f = e >> 6, eo = e & 63;
        int id = lattice[row * 4 + f];
        x[idx] = lat_emb[id * 64 + eo];
    } else {
        int k = idx - SEQ * 256;
        if (k < T_STEPS * 512) {
            int t = k >> 9, d = k & 511;
            float val;
            if (d < 256) {
                int f = d >> 6, eo = d & 63;
                int id = (t == 0) ? sos[f]
                                  : lattice[(((t - 1) * A_DIM) + gold[t - 1]) * 4 + f];
                val = lat_emb[id * 64 + eo];
            } else {
                val = in_emb[inputs[t] * 256 + (d - 256)];
            }
            decin[k] = val;
        }
    }
}

// ---------------------------------------------------------------------------
// Generic fp32 GEMM: C[m,n] = bias[n] + sum_k A[m*lda+k] * B[n*ldbn + k*ldbk]
// ---------------------------------------------------------------------------
__global__ __launch_bounds__(256) void k_gemm(
    const float* __restrict__ A, int lda, long sA,
    const float* __restrict__ B, int ldbn, int ldbk, long sB,
    const float* __restrict__ bias, int sBias,
    float* __restrict__ C, int ldc, long sC,
    int M, int N, int K)
{
    int b = blockIdx.z;
    A += b * sA; B += b * sB; C += b * sC;
    if (bias) bias += (long)b * sBias;
    int n0 = blockIdx.x * 64, m0 = blockIdx.y * 64;
    __shared__ float As[64][17];
    __shared__ float Bs[64][17];
    int tid = threadIdx.x;
    int tn = tid & 15, tm = tid >> 4;
    float acc[4][4] = {};
    int lk = tid & 15, lr = tid >> 4;
    for (int k0 = 0; k0 < K; k0 += 16) {
#pragma unroll
        for (int i = 0; i < 4; i++) {
            int row = lr + i * 16;
            int am = m0 + row;
            As[row][lk] = (am < M) ? A[(long)am * lda + k0 + lk] : 0.f;
            int bn = n0 + row;
            Bs[row][lk] = (bn < N) ? B[(long)bn * ldbn + (long)(k0 + lk) * ldbk] : 0.f;
        }
        __syncthreads();
#pragma unroll
        for (int k = 0; k < 16; k++) {
            float av[4], bv[4];
#pragma unroll
            for (int i = 0; i < 4; i++) av[i] = As[tm * 4 + i][k];
#pragma unroll
            for (int j = 0; j < 4; j++) bv[j] = Bs[tn * 4 + j][k];
#pragma unroll
            for (int i = 0; i < 4; i++)
#pragma unroll
                for (int j = 0; j < 4; j++) acc[i][j] += av[i] * bv[j];
        }
        __syncthreads();
    }
#pragma unroll
    for (int i = 0; i < 4; i++) {
        int m = m0 + tm * 4 + i;
        if (m >= M) continue;
#pragma unroll
        for (int j = 0; j < 4; j++) {
            int n = n0 + tn * 4 + j;
            if (n < N) C[(long)m * ldc + n] = acc[i][j] + (bias ? bias[n] : 0.f);
        }
    }
}

// ---------------------------------------------------------------------------
// Encoder biLSTM recurrence, one layer. ONE CU per direction (grid=2, 512
// threads, 8 waves, 2/SIMD -> 256-reg cap). Thread (p=tid>>8, j=tid&255)
// computes all 4 gate rows of unit j over K-half p. Wave-uniform p => a wave
// needs only its 64 h-pairs: 1 ds_read_b32/lane, then readlane -> SGPR feeds
// v_dot2's scalar slot (1:4 readlane:dot ratio). Weights: 48 pairs/row in
// arch VGPRs (192 regs; staging kept at ~8 transient regs via float2 +
// unroll 4 so the allocator does NOT shift weights to AGPR — r5's failure) +
// 16 pairs/row streamed from LDS (128 KB/step, DS pipe overlaps VALU).
// K-half partials join via 4 KB LDS. Two barriers/step, zero cross-CU.
// ---------------------------------------------------------------------------
__global__ __launch_bounds__(512, 2) void k_rec_enc(
    const float* __restrict__ pre,   // [2][SEQ][GE]
    const float* __restrict__ Whh,   // [2][GE][HE]
    float* __restrict__ y,           // [SEQ][512]
    float* __restrict__ hfin,        // [512] this layer's slot
    float* __restrict__ cfin)        // [512]
{
    const int tid = threadIdx.x;
    const int j = tid & 255;                      // hidden unit
    const int p = tid >> 8;                       // K-half (wave-uniform)
    const int lane = tid & 63;
    const int dir = blockIdx.x;
    const bool fwd = (dir == 0);
    const float* pre_d = pre + (size_t)dir * SEQ * GE;

    __shared__ uint32_t LDSW[16 * 512 * 4];       // 128 KB: pairs 48..63 per row
    __shared__ float part[4][256];                // 4 KB: p=1 partial sums
    __shared__ __align__(8) _Float16 hbuf[2][HE]; // 1 KB double-buffered h

    // stage weights: 4 gate rows x pairs [p*64, p*64+64). Pairs 0..47 ->
    // VGPR, 48..63 -> LDS column tid. float2 loads + unroll 4 keep transient
    // register pressure ~8 (r5's float4 full-unroll peaked ~290 -> AGPR).
    h2_t w[4][48];
#pragma unroll
    for (int g2 = 0; g2 < 4; g2++) {
        const float2* wr = (const float2*)(Whh + (size_t)dir * GE * HE
                                               + (size_t)(g2 * HE + j) * HE + p * 128);
#pragma unroll 4
        for (int i = 0; i < 48; i++) {
            float2 v = wr[i];
            w[g2][i] = h2_t{(_Float16)v.x, (_Float16)v.y};
        }
#pragma unroll 4
        for (int i = 48; i < 64; i++) {
            float2 v = wr[i];
            int pr = i - 48;                      // local pair idx 0..15
            LDSW[((g2 * 4 + (pr >> 2)) * 512 + tid) * 4 + (pr & 3)] = pkf16(v.x, v.y);
        }
    }
    if (tid < HE) hbuf[0][tid] = (_Float16)0.f;

    float c = 0.f, h_cur = 0.f;
    float pc0 = 0.f, pc1 = 0.f, pc2 = 0.f, pc3 = 0.f;
    if (p == 0) {
        const float* pp = pre_d + (size_t)(fwd ? 0 : SEQ - 1) * GE + j;
        pc0 = pp[0]; pc1 = pp[256]; pc2 = pp[512]; pc3 = pp[768];
    }
    __syncthreads();

    for (int s = 0; s < SEQ; s++) {
        const int t = fwd ? s : SEQ - 1 - s;
        // prefetch next step's pre-activations (p=0 only; vmcnt, hidden)
        float pn0 = 0.f, pn1 = 0.f, pn2 = 0.f, pn3 = 0.f;
        if (p == 0 && s + 1 < SEQ) {
            const float* pp = pre_d + (size_t)(fwd ? t + 1 : t - 1) * GE + j;
            pn0 = pp[0]; pn1 = pp[256]; pn2 = pp[512]; pn3 = pp[768];
        }

        // lane l holds h-pair dword (p*64 + l); readlane k => pair p*64+k
        uint32_t hreg = ((const uint32_t*)hbuf[s & 1])[p * 64 + lane];

        float a0 = 0.f, a1 = 0.f, a2 = 0.f, a3 = 0.f;
#pragma unroll
        for (int kb = 0; kb < 12; kb++) {         // pairs 0..47 (VGPR weights)
            const int k = kb * 4;
            h2_t h0 = hlane(hreg, k + 0);
            h2_t h1 = hlane(hreg, k + 1);
            h2_t h2v = hlane(hreg, k + 2);
            h2_t h3 = hlane(hreg, k + 3);
            a0 = fdot2f(w[0][k + 0], h0, a0); a1 = fdot2f(w[1][k + 0], h0, a1);
            a2 = fdot2f(w[2][k + 0], h0, a2); a3 = fdot2f(w[3][k + 0], h0, a3);
            a0 = fdot2f(w[0][k + 1], h1, a0); a1 = fdot2f(w[1][k + 1], h1, a1);
            a2 = fdot2f(w[2][k + 1], h1, a2); a3 = fdot2f(w[3][k + 1], h1, a3);
            a0 = fdot2f(w[0][k + 2], h2v, a0); a1 = fdot2f(w[1][k + 2], h2v, a1);
            a2 = fdot2f(w[2][k + 2], h2v, a2); a3 = fdot2f(w[3][k + 2], h2v, a3);
            a0 = fdot2f(w[0][k + 3], h3, a0); a1 = fdot2f(w[1][k + 3], h3, a1);
            a2 = fdot2f(w[2][k + 3], h3, a2); a3 = fdot2f(w[3][k + 3], h3, a3);
        }
#pragma unroll
        for (int grp = 0; grp < 4; grp++) {       // pairs 48..63 (LDS weights)
            uint4 b0 = *(const uint4*)&LDSW[((0 * 4 + grp) * 512 + tid) * 4];
            uint4 b1 = *(const uint4*)&LDSW[((1 * 4 + grp) * 512 + tid) * 4];
            uint4 b2 = *(const uint4*)&LDSW[((2 * 4 + grp) * 512 + tid) * 4];
            uint4 b3 = *(const uint4*)&LDSW[((3 * 4 + grp) * 512 + tid) * 4];
            const int k = 48 + grp * 4;
            h2_t h0 = hlane(hreg, k + 0);
            h2_t h1 = hlane(hreg, k + 1);
            h2_t h2v = hlane(hreg, k + 2);
            h2_t h3 = hlane(hreg, k + 3);
            a0 = fdot2f(__builtin_bit_cast(h2_t, b0.x), h0, a0);
            a1 = fdot2f(__builtin_bit_cast(h2_t, b1.x), h0, a1);
            a2 = fdot2f(__builtin_bit_cast(h2_t, b2.x), h0, a2);
            a3 = fdot2f(__builtin_bit_cast(h2_t, b3.x), h0, a3);
            a0 = fdot2f(__builtin_bit_cast(h2_t, b0.y), h1, a0);
            a1 = fdot2f(__builtin_bit_cast(h2_t, b1.y), h1, a1);
            a2 = fdot2f(__builtin_bit_cast(h2_t, b2.y), h1, a2);
            a3 = fdot2f(__builtin_bit_cast(h2_t, b3.y), h1, a3);
            a0 = fdot2f(__builtin_bit_cast(h2_t, b0.z), h2v, a0);
            a1 = fdot2f(__builtin_bit_cast(h2_t, b1.z), h2v, a1);
            a2 = fdot2f(__builtin_bit_cast(h2_t, b2.z), h2v, a2);
            a3 = fdot2f(__builtin_bit_cast(h2_t, b3.z), h2v, a3);
            a0 = fdot2f(__builtin_bit_cast(h2_t, b0.w), h3, a0);
            a1 = fdot2f(__builtin_bit_cast(h2_t, b1.w), h3, a1);
            a2 = fdot2f(__builtin_bit_cast(h2_t, b2.w), h3, a2);
            a3 = fdot2f(__builtin_bit_cast(h2_t, b3.w), h3, a3);
        }

        if (p == 1) {
            part[0][j] = a0; part[1][j] = a1; part[2][j] = a2; part[3][j] = a3;
        }
        __syncthreads();                          // partials visible
        if (p == 0) {
            float gi = pc0 + (a0 + part[0][j]);
            float gf = pc1 + (a1 + part[1][j]);
            float gg = pc2 + (a2 + part[2][j]);
            float go = pc3 + (a3 + part[3][j]);
            pc0 = pn0; pc1 = pn1; pc2 = pn2; pc3 = pn3;
            c = sigf(gf) * c + sigf(gi) * tanh_fast(gg);
            h_cur = sigf(go) * tanh_fast(c);
            y[(size_t)t * 512 + dir * HE + j] = h_cur;
            hbuf[(s + 1) & 1][j] = (_Float16)h_cur;
        }
        __syncthreads();                          // h_t + part[] reuse safe
    }
    if (p == 0) {
        hfin[dir * HE + j] = h_cur;
        cfin[dir * HE + j] = c;
    }
}

// ---------------------------------------------------------------------------
// Decoder LSTM recurrence, one layer. 16 blocks; block r owns h[r*32..+32).
// Row K=512 split across thread pairs (256 f16 weights each). Proven r0
// protocol (agent-scope self-validating comm words).
// ---------------------------------------------------------------------------
__global__ __launch_bounds__(256, 1) void k_rec_dec(
    const float* __restrict__ pre,    // [64][GD]
    const float* __restrict__ Whh,    // [GD][DH] (layer-selected)
    const float* __restrict__ hinit,  // [512]
    const float* __restrict__ cinit,  // [512]
    float* __restrict__ hseq,         // [64][512]
    float* __restrict__ comm)         // [64][512], zeroed before launch
{
    const int tid = threadIdx.x, r = blockIdx.x;
    const int kh = tid >> 7, rem = tid & 127;
    const int q = rem >> 5, jj = rem & 31;
    const int row = q * DH + r * 32 + jj;
    const int k0 = kh * 256;

    h2_t w2[128];
    {
        const float4* wr = (const float4*)(Whh + (long)row * DH + k0);
#pragma unroll
        for (int i = 0; i < 64; i++) {
            float4 v = wr[i];
            w2[2 * i]     = h2_t{(_Float16)v.x, (_Float16)v.y};
            w2[2 * i + 1] = h2_t{(_Float16)v.z, (_Float16)v.w};
        }
    }

    __shared__ __align__(16) _Float16 hsArr[DH];
    __shared__ float part[256];
    __shared__ float gate[128];
    hsArr[tid] = (_Float16)hinit[tid];
    hsArr[tid + 256] = (_Float16)hinit[tid + 256];
    float c = (tid < 32) ? cinit[r * 32 + tid] : 0.f;
    float pre_cur = (tid < 128) ? pre[row] : 0.f;
    float h_cur = 0.f;
    __syncthreads();

    for (int s = 0; s < T_STEPS; s++) {
        float acc = 0.f;
        const float4* hv = (const float4*)(hsArr + k0);
#pragma unroll
        for (int kk = 0; kk < 32; kk++) {
            float4 blk = hv[kk];
            const h2_t* hp = (const h2_t*)&blk;
            acc = fdot2f(w2[4 * kk + 0], hp[0], acc);
            acc = fdot2f(w2[4 * kk + 1], hp[1], acc);
            acc = fdot2f(w2[4 * kk + 2], hp[2], acc);
            acc = fdot2f(w2[4 * kk + 3], hp[3], acc);
        }
        part[tid] = acc;
        __syncthreads();
        if (tid < 128) {
            float g = part[tid] + part[tid + 128] + pre_cur;
            if (s + 1 < T_STEPS) pre_cur = pre[(long)(s + 1) * GD + row];
            gate[tid] = g;
        }
        __syncthreads();
        if (tid < 32) {
            int jg = r * 32 + tid;
            float gi = gate[tid], gf = gate[32 + tid], gg = gate[64 + tid], go = gate[96 + tid];
            c = sigf(gf) * c + sigf(gi) * tanh_fast(gg);
            h_cur = sigf(go) * tanh_fast(c);
            post_comm(&comm[(long)s * DH + jg], h_cur);
            hseq[(long)s * DH + jg] = h_cur;
            hsArr[jg] = (_Float16)h_cur;
        }
        if (s + 1 < T_STEPS) {
            if (tid < 224) {                       // remote rel offsets 32..255
                int idx = (r * 32 + 32 + tid) & 511;
                hsArr[idx] = (_Float16)poll_comm(&comm[(long)s * DH + idx]);
            }
            {                                      // remote rel offsets 256..511
                int idx = (r * 32 + 256 + tid) & 511;
                hsArr[idx] = (_Float16)poll_comm(&comm[(long)s * DH + idx]);
            }
        }
        __syncthreads();
    }
}

// ---------------------------------------------------------------------------
// Attention readout
// ---------------------------------------------------------------------------
__global__ void k_attn(const float* __restrict__ encK, const float* __restrict__ qs,
                       const float* __restrict__ v, const int* __restrict__ alens,
                       float* __restrict__ out)
{
    int t = blockIdx.x;
    int tid = threadIdx.x;
    int wave = tid >> 6, lane = tid & 63;
    int len = alens[t];
    const float* qt = qs + t * 256;
    for (int a = wave; a < A_DIM; a += 4) {
        const float* ek = encK + (long)(t * A_DIM + a) * 256;
        float sum = 0.f;
#pragma unroll
        for (int e = 0; e < 4; e++) {
            int d = lane * 4 + e;
            sum += v[d] * tanhf(ek[d] + qt[d]);
        }
        for (int off = 32; off; off >>= 1) sum += __shfl_down(sum, off, 64);
        if (lane == 0) out[t * A_DIM + a] = (a < len) ? sum : -1e10f;
    }
}

// ---------------------------------------------------------------------------
extern "C" void kernel_launch(void* const* d_in, const int* in_sizes, int n_in,
                              void* d_out, int out_size, void* d_ws, size_t ws_size,
                              hipStream_t stream)
{
    (void)in_sizes; (void)n_in; (void)out_size; (void)ws_size;
    const int*   lattice = (const int*)d_in[0];
    const int*   alens   = (const int*)d_in[1];
    const int*   inputs  = (const int*)d_in[2];
    const int*   gold    = (const int*)d_in[4];
    const int*   sos     = (const int*)d_in[5];
    const float* lat_emb = (const float*)d_in[6];
    const float* in_emb  = (const float*)d_in[7];
    const float* Wih0    = (const float*)d_in[8];
    const float* Whh0    = (const float*)d_in[9];
    const float* b0      = (const float*)d_in[10];
    const float* Wih1    = (const float*)d_in[11];
    const float* Whh1    = (const float*)d_in[12];
    const float* b1      = (const float*)d_in[13];
    const float* dWih    = (const float*)d_in[14];
    const float* dWhh    = (const float*)d_in[15];
    const float* db      = (const float*)d_in[16];
    const float* Wq      = (const float*)d_in[17];
    const float* Wk      = (const float*)d_in[18];
    const float* av      = (const float*)d_in[19];
    float* out = (float*)d_out;
    float* ws  = (float*)d_ws;

    // ws layout (floats) — total 3,770,368 floats = 15.08 MB (≤15.7 MB proven)
    float* comm  = ws;                  // 524288  (unused by encoder now)
    float* commD = ws + 524288;         // 65536   [2 layers][64][512]
    float* xbuf  = ws + 589824;         // 262144  x; later decoder scratch:
    float* dpre  = xbuf;                //   131072
    float* h0seq = xbuf + 131072;       //   32768
    float* h1seq = xbuf + 163840;       //   32768
    float* qseq  = xbuf + 196608;       //   16384
    float* pre   = ws + 851968;         // 2097152 (per-layer gate pre-activations)
    float* y0    = ws + 2949120;        // 524288  L0 output; reused as enc (L1 out)
    float* hdec  = ws + 3473408;        // 1024    [2][512]
    float* cdec  = ws + 3474432;        // 1024
    float* decin = ws + 3475456;        // 32768   [64][512]
    float* encK  = ws + 3508224;        // 262144
    (void)comm;

    // zero commD only (decoder polling protocol; encoder is barrier-only)
    hipMemsetAsync(commD, 0, 65536 * sizeof(float), stream);

    k_embed<<<1152, 256, 0, stream>>>(lattice, inputs, gold, sos, lat_emb, in_emb, xbuf, decin);

    // pre = x @ Wih0^T + b0  (both dirs)
    k_gemm<<<dim3(16, 16, 2), 256, 0, stream>>>(
        xbuf, 256, 0L, Wih0, 256, 1, (long)GE * 256, b0, GE,
        pre, GE, (long)SEQ * GE, SEQ, GE, 256);
    k_rec_enc<<<2, 512, 0, stream>>>(pre, Whh0, y0, hdec, cdec);

    // pre = y0 @ Wih1^T + b1
    k_gemm<<<dim3(16, 16, 2), 256, 0, stream>>>(
        y0, 512, 0L, Wih1, 512, 1, (long)GE * 512, b1, GE,
        pre, GE, (long)SEQ * GE, SEQ, GE, 512);
    // L1 output overwrites y0 region (y0 is dead after the GEMM above)
    k_rec_enc<<<2, 512, 0, stream>>>(pre, Whh1, y0, hdec + 512, cdec + 512);

    // encK = enc @ Wk
    k_gemm<<<dim3(4, 16, 1), 256, 0, stream>>>(
        y0, 512, 0L, Wk, 1, 256, 0L, nullptr, 0,
        encK, 256, 0L, SEQ, 256, 512);

    // dpre = decin @ dWih[0]^T + db[0]
    k_gemm<<<dim3(32, 1, 1), 256, 0, stream>>>(
        decin, 512, 0L, dWih, 512, 1, 0L, db, 0,
        dpre, GD, 0L, T_STEPS, GD, 512);
    k_rec_dec<<<16, 256, 0, stream>>>(dpre, dWhh, hdec, cdec, h0seq, commD);

    // dpre = h0seq @ dWih[1]^T + db[1]
    k_gemm<<<dim3(32, 1, 1), 256, 0, stream>>>(
        h0seq, 512, 0L, dWih + (long)GD * 512, 512, 1, 0L, db + GD, 0,
        dpre, GD, 0L, T_STEPS, GD, 512);
    k_rec_dec<<<16, 256, 0, stream>>>(dpre, dWhh + (long)GD * 512, hdec + 512, cdec + 512,
                                      h1seq, commD + 32768);

    // q = h1seq @ Wq
    k_gemm<<<dim3(4, 1, 1), 256, 0, stream>>>(
        h1seq, 512, 0L, Wq, 1, 256, 0L, nullptr, 0,
        qseq, 256, 0L, T_STEPS, 256, 512);

    k_attn<<<64, 256, 0, stream>>>(encK, qseq, av, alens, out);
}

// Round 7
// 4351.356 us; speedup vs baseline: 5.4795x; 5.4795x over previous
//
#include <hip/hip_runtime.h>
#include <math.h>
#include <stdint.h>

#define T_STEPS 64
#define A_DIM   16
#define SEQ     1024      // T*A
#define HE      256       // encoder hidden per direction
#define DH      512       // decoder hidden
#define GE      1024      // 4*HE
#define GD      2048      // 4*DH

typedef _Float16 h2_t __attribute__((ext_vector_type(2)));

__device__ __forceinline__ float sigf(float x) { return 1.f / (1.f + __expf(-x)); }
// tanh via exp2-based __expf; args here are bounded (|x| < ~4) so no overflow path.
__device__ __forceinline__ float tanh_fast(float x) {
    float e = __expf(-2.f * x);
    return (1.f - e) / (1.f + e);
}

__device__ __forceinline__ float fdot2f(h2_t a, h2_t b, float c) {
#if defined(__has_builtin) && __has_builtin(__builtin_amdgcn_fdot2)
    return __builtin_amdgcn_fdot2(a, b, c, false);
#else
    return c + (float)a.x * (float)b.x + (float)a.y * (float)b.y;
#endif
}

__device__ __forceinline__ uint32_t pkf16(float a, float b) {
    unsigned short x = __builtin_bit_cast(unsigned short, (_Float16)a);
    unsigned short y = __builtin_bit_cast(unsigned short, (_Float16)b);
    return (uint32_t)x | ((uint32_t)y << 16);
}

// readlane -> wave-uniform h pair (compiler keeps it in an SGPR and folds it
// into v_dot2's VOP3P scalar slot; no inline asm so the scheduler is free)
__device__ __forceinline__ h2_t hlane(uint32_t hreg, int l) {
    return __builtin_bit_cast(h2_t, (uint32_t)__builtin_amdgcn_readlane((int)hreg, l));
}

// Agent-scope self-validating comm words (decoder only). Lesson r1/r2:
// cross-CU exchange must use the L3 coherence point; no fast path exists.
__device__ __forceinline__ float poll_comm(const float* p) {
    float v;
    do {
        v = __hip_atomic_load(p, __ATOMIC_RELAXED, __HIP_MEMORY_SCOPE_AGENT);
    } while (v == 0.f);
    return v - 4.0f;
}

__device__ __forceinline__ void post_comm(float* p, float h) {
    __hip_atomic_store(p, h + 4.0f, __ATOMIC_RELAXED, __HIP_MEMORY_SCOPE_AGENT);
}

// ---------------------------------------------------------------------------
// Embedding / decoder-input assembly
// ---------------------------------------------------------------------------
__global__ void k_embed(const int* __restrict__ lattice, const int* __restrict__ inputs,
                        const int* __restrict__ gold, const int* __restrict__ sos,
                        const float* __restrict__ lat_emb, const float* __restrict__ in_emb,
                        float* __restrict__ x, float* __restrict__ decin)
{
    int idx = blockIdx.x * 256 + threadIdx.x;
    if (idx < SEQ * 256) {
        int row = idx >> 8, e = idx & 255;
        int f = e >> 6, eo = e & 63;
        int id = lattice[row * 4 + f];
        x[idx] = lat_emb[id * 64 + eo];
    } else {
        int k = idx - SEQ * 256;
        if (k < T_STEPS * 512) {
            int t = k >> 9, d = k & 511;
            float val;
            if (d < 256) {
                int f = d >> 6, eo = d & 63;
                int id = (t == 0) ? sos[f]
                                  : lattice[(((t - 1) * A_DIM) + gold[t - 1]) * 4 + f];
                val = lat_emb[id * 64 + eo];
            } else {
                val = in_emb[inputs[t] * 256 + (d - 256)];
            }
            decin[k] = val;
        }
    }
}

// ---------------------------------------------------------------------------
// Generic fp32 GEMM: C[m,n] = bias[n] + sum_k A[m*lda+k] * B[n*ldbn + k*ldbk]
// ---------------------------------------------------------------------------
__global__ __launch_bounds__(256) void k_gemm(
    const float* __restrict__ A, int lda, long sA,
    const float* __restrict__ B, int ldbn, int ldbk, long sB,
    const float* __restrict__ bias, int sBias,
    float* __restrict__ C, int ldc, long sC,
    int M, int N, int K)
{
    int b = blockIdx.z;
    A += b * sA; B += b * sB; C += b * sC;
    if (bias) bias += (long)b * sBias;
    int n0 = blockIdx.x * 64, m0 = blockIdx.y * 64;
    __shared__ float As[64][17];
    __shared__ float Bs[64][17];
    int tid = threadIdx.x;
    int tn = tid & 15, tm = tid >> 4;
    float acc[4][4] = {};
    int lk = tid & 15, lr = tid >> 4;
    for (int k0 = 0; k0 < K; k0 += 16) {
#pragma unroll
        for (int i = 0; i < 4; i++) {
            int row = lr + i * 16;
            int am = m0 + row;
            As[row][lk] = (am < M) ? A[(long)am * lda + k0 + lk] : 0.f;
            int bn = n0 + row;
            Bs[row][lk] = (bn < N) ? B[(long)bn * ldbn + (long)(k0 + lk) * ldbk] : 0.f;
        }
        __syncthreads();
#pragma unroll
        for (int k = 0; k < 16; k++) {
            float av[4], bv[4];
#pragma unroll
            for (int i = 0; i < 4; i++) av[i] = As[tm * 4 + i][k];
#pragma unroll
            for (int j = 0; j < 4; j++) bv[j] = Bs[tn * 4 + j][k];
#pragma unroll
            for (int i = 0; i < 4; i++)
#pragma unroll
                for (int j = 0; j < 4; j++) acc[i][j] += av[i] * bv[j];
        }
        __syncthreads();
    }
#pragma unroll
    for (int i = 0; i < 4; i++) {
        int m = m0 + tm * 4 + i;
        if (m >= M) continue;
#pragma unroll
        for (int j = 0; j < 4; j++) {
            int n = n0 + tn * 4 + j;
            if (n < N) C[(long)m * ldc + n] = acc[i][j] + (bias ? bias[n] : 0.f);
        }
    }
}

// ---------------------------------------------------------------------------
// Encoder biLSTM recurrence, one layer. ONE CU per direction (grid=2, 512
// threads, 8 waves, 2/SIMD -> 256-reg cap). Thread (p=tid>>8, j=tid&255)
// computes all 4 gate rows of unit j over K-half p. Wave-uniform p => a wave
// needs only its 64 h-pairs: 1 ds_read_b32/lane, then readlane -> SGPR feeds
// v_dot2's scalar slot (1:4 readlane:dot ratio). Weights: 48 pairs/row in
// arch VGPRs (192 regs) + 16 pairs/row streamed from LDS (128 KB/step, DS
// pipe overlaps VALU). K-half partials join via 4 KB LDS. Two barriers/step.
//
// REGISTER-ALLOCATION DISCIPLINE (r5/r6 lessons):
//  - staging is FULLY unrolled: every w[g][i] index is compile-time constant
//    (runtime index => array demoted to scratch; r6 = 6x slowdown, VGPR=88).
//  - sched_barrier(0) every 8 pairs caps the staged-load window so the
//    compiler can't hoist 192 float2 loads into one transient spike (r5's
//    ~290-reg peak pushed the weights into AGPRs; asm "v" constraints then
//    forced accvgpr_read copies on every dot).
//  - dot loop uses the fdot2 BUILTIN only — no inline asm, no class pinning.
// ---------------------------------------------------------------------------
__global__ __launch_bounds__(512, 2) void k_rec_enc(
    const float* __restrict__ pre,   // [2][SEQ][GE]
    const float* __restrict__ Whh,   // [2][GE][HE]
    float* __restrict__ y,           // [SEQ][512]
    float* __restrict__ hfin,        // [512] this layer's slot
    float* __restrict__ cfin)        // [512]
{
    const int tid = threadIdx.x;
    const int j = tid & 255;                      // hidden unit
    const int p = tid >> 8;                       // K-half (wave-uniform)
    const int lane = tid & 63;
    const int dir = blockIdx.x;
    const bool fwd = (dir == 0);
    const float* pre_d = pre + (size_t)dir * SEQ * GE;

    __shared__ uint32_t LDSW[16 * 512 * 4];       // 128 KB: pairs 48..63 per row
    __shared__ float part[4][256];                // 4 KB: p=1 partial sums
    __shared__ __align__(8) _Float16 hbuf[2][HE]; // 1 KB double-buffered h

    // stage weights: 4 gate rows x pairs [p*64, p*64+64). Pairs 0..47 ->
    // VGPR, 48..63 -> LDS column tid. Fully unrolled, windowed by
    // sched_barrier(0) every 8 pairs (see header comment).
    h2_t w[4][48];
#pragma unroll
    for (int g2 = 0; g2 < 4; g2++) {
        const float2* wr = (const float2*)(Whh + (size_t)dir * GE * HE
                                               + (size_t)(g2 * HE + j) * HE + p * 128);
#pragma unroll
        for (int i = 0; i < 48; i++) {
            float2 v = wr[i];
            w[g2][i] = h2_t{(_Float16)v.x, (_Float16)v.y};
            if ((i & 7) == 7) __builtin_amdgcn_sched_barrier(0);
        }
#pragma unroll
        for (int i = 48; i < 64; i++) {
            float2 v = wr[i];
            int pr = i - 48;                      // local pair idx 0..15
            LDSW[((g2 * 4 + (pr >> 2)) * 512 + tid) * 4 + (pr & 3)] = pkf16(v.x, v.y);
            if ((i & 7) == 7) __builtin_amdgcn_sched_barrier(0);
        }
    }
    if (tid < HE) hbuf[0][tid] = (_Float16)0.f;

    float c = 0.f, h_cur = 0.f;
    float pc0 = 0.f, pc1 = 0.f, pc2 = 0.f, pc3 = 0.f;
    if (p == 0) {
        const float* pp = pre_d + (size_t)(fwd ? 0 : SEQ - 1) * GE + j;
        pc0 = pp[0]; pc1 = pp[256]; pc2 = pp[512]; pc3 = pp[768];
    }
    __syncthreads();

    for (int s = 0; s < SEQ; s++) {
        const int t = fwd ? s : SEQ - 1 - s;
        // prefetch next step's pre-activations (p=0 only; vmcnt, hidden)
        float pn0 = 0.f, pn1 = 0.f, pn2 = 0.f, pn3 = 0.f;
        if (p == 0 && s + 1 < SEQ) {
            const float* pp = pre_d + (size_t)(fwd ? t + 1 : t - 1) * GE + j;
            pn0 = pp[0]; pn1 = pp[256]; pn2 = pp[512]; pn3 = pp[768];
        }

        // lane l holds h-pair dword (p*64 + l); readlane k => pair p*64+k
        uint32_t hreg = ((const uint32_t*)hbuf[s & 1])[p * 64 + lane];

        float a0 = 0.f, a1 = 0.f, a2 = 0.f, a3 = 0.f;
#pragma unroll
        for (int kb = 0; kb < 12; kb++) {         // pairs 0..47 (VGPR weights)
            const int k = kb * 4;
            h2_t h0 = hlane(hreg, k + 0);
            h2_t h1 = hlane(hreg, k + 1);
            h2_t h2v = hlane(hreg, k + 2);
            h2_t h3 = hlane(hreg, k + 3);
            a0 = fdot2f(w[0][k + 0], h0, a0); a1 = fdot2f(w[1][k + 0], h0, a1);
            a2 = fdot2f(w[2][k + 0], h0, a2); a3 = fdot2f(w[3][k + 0], h0, a3);
            a0 = fdot2f(w[0][k + 1], h1, a0); a1 = fdot2f(w[1][k + 1], h1, a1);
            a2 = fdot2f(w[2][k + 1], h1, a2); a3 = fdot2f(w[3][k + 1], h1, a3);
            a0 = fdot2f(w[0][k + 2], h2v, a0); a1 = fdot2f(w[1][k + 2], h2v, a1);
            a2 = fdot2f(w[2][k + 2], h2v, a2); a3 = fdot2f(w[3][k + 2], h2v, a3);
            a0 = fdot2f(w[0][k + 3], h3, a0); a1 = fdot2f(w[1][k + 3], h3, a1);
            a2 = fdot2f(w[2][k + 3], h3, a2); a3 = fdot2f(w[3][k + 3], h3, a3);
        }
#pragma unroll
        for (int grp = 0; grp < 4; grp++) {       // pairs 48..63 (LDS weights)
            uint4 b0 = *(const uint4*)&LDSW[((0 * 4 + grp) * 512 + tid) * 4];
            uint4 b1 = *(const uint4*)&LDSW[((1 * 4 + grp) * 512 + tid) * 4];
            uint4 b2 = *(const uint4*)&LDSW[((2 * 4 + grp) * 512 + tid) * 4];
            uint4 b3 = *(const uint4*)&LDSW[((3 * 4 + grp) * 512 + tid) * 4];
            const int k = 48 + grp * 4;
            h2_t h0 = hlane(hreg, k + 0);
            h2_t h1 = hlane(hreg, k + 1);
            h2_t h2v = hlane(hreg, k + 2);
            h2_t h3 = hlane(hreg, k + 3);
            a0 = fdot2f(__builtin_bit_cast(h2_t, b0.x), h0, a0);
            a1 = fdot2f(__builtin_bit_cast(h2_t, b1.x), h0, a1);
            a2 = fdot2f(__builtin_bit_cast(h2_t, b2.x), h0, a2);
            a3 = fdot2f(__builtin_bit_cast(h2_t, b3.x), h0, a3);
            a0 = fdot2f(__builtin_bit_cast(h2_t, b0.y), h1, a0);
            a1 = fdot2f(__builtin_bit_cast(h2_t, b1.y), h1, a1);
            a2 = fdot2f(__builtin_bit_cast(h2_t, b2.y), h1, a2);
            a3 = fdot2f(__builtin_bit_cast(h2_t, b3.y), h1, a3);
            a0 = fdot2f(__builtin_bit_cast(h2_t, b0.z), h2v, a0);
            a1 = fdot2f(__builtin_bit_cast(h2_t, b1.z), h2v, a1);
            a2 = fdot2f(__builtin_bit_cast(h2_t, b2.z), h2v, a2);
            a3 = fdot2f(__builtin_bit_cast(h2_t, b3.z), h2v, a3);
            a0 = fdot2f(__builtin_bit_cast(h2_t, b0.w), h3, a0);
            a1 = fdot2f(__builtin_bit_cast(h2_t, b1.w), h3, a1);
            a2 = fdot2f(__builtin_bit_cast(h2_t, b2.w), h3, a2);
            a3 = fdot2f(__builtin_bit_cast(h2_t, b3.w), h3, a3);
        }

        if (p == 1) {
            part[0][j] = a0; part[1][j] = a1; part[2][j] = a2; part[3][j] = a3;
        }
        __syncthreads();                          // partials visible
        if (p == 0) {
            float gi = pc0 + (a0 + part[0][j]);
            float gf = pc1 + (a1 + part[1][j]);
            float gg = pc2 + (a2 + part[2][j]);
            float go = pc3 + (a3 + part[3][j]);
            pc0 = pn0; pc1 = pn1; pc2 = pn2; pc3 = pn3;
            c = sigf(gf) * c + sigf(gi) * tanh_fast(gg);
            h_cur = sigf(go) * tanh_fast(c);
            y[(size_t)t * 512 + dir * HE + j] = h_cur;
            hbuf[(s + 1) & 1][j] = (_Float16)h_cur;
        }
        __syncthreads();                          // h_t + part[] reuse safe
    }
    if (p == 0) {
        hfin[dir * HE + j] = h_cur;
        cfin[dir * HE + j] = c;
    }
}

// ---------------------------------------------------------------------------
// Decoder LSTM recurrence, one layer. 16 blocks; block r owns h[r*32..+32).
// Row K=512 split across thread pairs (256 f16 weights each). Proven r0
// protocol (agent-scope self-validating comm words).
// ---------------------------------------------------------------------------
__global__ __launch_bounds__(256, 1) void k_rec_dec(
    const float* __restrict__ pre,    // [64][GD]
    const float* __restrict__ Whh,    // [GD][DH] (layer-selected)
    const float* __restrict__ hinit,  // [512]
    const float* __restrict__ cinit,  // [512]
    float* __restrict__ hseq,         // [64][512]
    float* __restrict__ comm)         // [64][512], zeroed before launch
{
    const int tid = threadIdx.x, r = blockIdx.x;
    const int kh = tid >> 7, rem = tid & 127;
    const int q = rem >> 5, jj = rem & 31;
    const int row = q * DH + r * 32 + jj;
    const int k0 = kh * 256;

    h2_t w2[128];
    {
        const float4* wr = (const float4*)(Whh + (long)row * DH + k0);
#pragma unroll
        for (int i = 0; i < 64; i++) {
            float4 v = wr[i];
            w2[2 * i]     = h2_t{(_Float16)v.x, (_Float16)v.y};
            w2[2 * i + 1] = h2_t{(_Float16)v.z, (_Float16)v.w};
        }
    }

    __shared__ __align__(16) _Float16 hsArr[DH];
    __shared__ float part[256];
    __shared__ float gate[128];
    hsArr[tid] = (_Float16)hinit[tid];
    hsArr[tid + 256] = (_Float16)hinit[tid + 256];
    float c = (tid < 32) ? cinit[r * 32 + tid] : 0.f;
    float pre_cur = (tid < 128) ? pre[row] : 0.f;
    float h_cur = 0.f;
    __syncthreads();

    for (int s = 0; s < T_STEPS; s++) {
        float acc = 0.f;
        const float4* hv = (const float4*)(hsArr + k0);
#pragma unroll
        for (int kk = 0; kk < 32; kk++) {
            float4 blk = hv[kk];
            const h2_t* hp = (const h2_t*)&blk;
            acc = fdot2f(w2[4 * kk + 0], hp[0], acc);
            acc = fdot2f(w2[4 * kk + 1], hp[1], acc);
            acc = fdot2f(w2[4 * kk + 2], hp[2], acc);
            acc = fdot2f(w2[4 * kk + 3], hp[3], acc);
        }
        part[tid] = acc;
        __syncthreads();
        if (tid < 128) {
            float g = part[tid] + part[tid + 128] + pre_cur;
            if (s + 1 < T_STEPS) pre_cur = pre[(long)(s + 1) * GD + row];
            gate[tid] = g;
        }
        __syncthreads();
        if (tid < 32) {
            int jg = r * 32 + tid;
            float gi = gate[tid], gf = gate[32 + tid], gg = gate[64 + tid], go = gate[96 + tid];
            c = sigf(gf) * c + sigf(gi) * tanh_fast(gg);
            h_cur = sigf(go) * tanh_fast(c);
            post_comm(&comm[(long)s * DH + jg], h_cur);
            hseq[(long)s * DH + jg] = h_cur;
            hsArr[jg] = (_Float16)h_cur;
        }
        if (s + 1 < T_STEPS) {
            if (tid < 224) {                       // remote rel offsets 32..255
                int idx = (r * 32 + 32 + tid) & 511;
                hsArr[idx] = (_Float16)poll_comm(&comm[(long)s * DH + idx]);
            }
            {                                      // remote rel offsets 256..511
                int idx = (r * 32 + 256 + tid) & 511;
                hsArr[idx] = (_Float16)poll_comm(&comm[(long)s * DH + idx]);
            }
        }
        __syncthreads();
    }
}

// ---------------------------------------------------------------------------
// Attention readout
// ---------------------------------------------------------------------------
__global__ void k_attn(const float* __restrict__ encK, const float* __restrict__ qs,
                       const float* __restrict__ v, const int* __restrict__ alens,
                       float* __restrict__ out)
{
    int t = blockIdx.x;
    int tid = threadIdx.x;
    int wave = tid >> 6, lane = tid & 63;
    int len = alens[t];
    const float* qt = qs + t * 256;
    for (int a = wave; a < A_DIM; a += 4) {
        const float* ek = encK + (long)(t * A_DIM + a) * 256;
        float sum = 0.f;
#pragma unroll
        for (int e = 0; e < 4; e++) {
            int d = lane * 4 + e;
            sum += v[d] * tanhf(ek[d] + qt[d]);
        }
        for (int off = 32; off; off >>= 1) sum += __shfl_down(sum, off, 64);
        if (lane == 0) out[t * A_DIM + a] = (a < len) ? sum : -1e10f;
    }
}

// ---------------------------------------------------------------------------
extern "C" void kernel_launch(void* const* d_in, const int* in_sizes, int n_in,
                              void* d_out, int out_size, void* d_ws, size_t ws_size,
                              hipStream_t stream)
{
    (void)in_sizes; (void)n_in; (void)out_size; (void)ws_size;
    const int*   lattice = (const int*)d_in[0];
    const int*   alens   = (const int*)d_in[1];
    const int*   inputs  = (const int*)d_in[2];
    const int*   gold    = (const int*)d_in[4];
    const int*   sos     = (const int*)d_in[5];
    const float* lat_emb = (const float*)d_in[6];
    const float* in_emb  = (const float*)d_in[7];
    const float* Wih0    = (const float*)d_in[8];
    const float* Whh0    = (const float*)d_in[9];
    const float* b0      = (const float*)d_in[10];
    const float* Wih1    = (const float*)d_in[11];
    const float* Whh1    = (const float*)d_in[12];
    const float* b1      = (const float*)d_in[13];
    const float* dWih    = (const float*)d_in[14];
    const float* dWhh    = (const float*)d_in[15];
    const float* db      = (const float*)d_in[16];
    const float* Wq      = (const float*)d_in[17];
    const float* Wk      = (const float*)d_in[18];
    const float* av      = (const float*)d_in[19];
    float* out = (float*)d_out;
    float* ws  = (float*)d_ws;

    // ws layout (floats) — total 3,770,368 floats = 15.08 MB (≤15.7 MB proven)
    float* comm  = ws;                  // 524288  (unused by encoder now)
    float* commD = ws + 524288;         // 65536   [2 layers][64][512]
    float* xbuf  = ws + 589824;         // 262144  x; later decoder scratch:
    float* dpre  = xbuf;                //   131072
    float* h0seq = xbuf + 131072;       //   32768
    float* h1seq = xbuf + 163840;       //   32768
    float* qseq  = xbuf + 196608;       //   16384
    float* pre   = ws + 851968;         // 2097152 (per-layer gate pre-activations)
    float* y0    = ws + 2949120;        // 524288  L0 output; reused as enc (L1 out)
    float* hdec  = ws + 3473408;        // 1024    [2][512]
    float* cdec  = ws + 3474432;        // 1024
    float* decin = ws + 3475456;        // 32768   [64][512]
    float* encK  = ws + 3508224;        // 262144
    (void)comm;

    // zero commD only (decoder polling protocol; encoder is barrier-only)
    hipMemsetAsync(commD, 0, 65536 * sizeof(float), stream);

    k_embed<<<1152, 256, 0, stream>>>(lattice, inputs, gold, sos, lat_emb, in_emb, xbuf, decin);

    // pre = x @ Wih0^T + b0  (both dirs)
    k_gemm<<<dim3(16, 16, 2), 256, 0, stream>>>(
        xbuf, 256, 0L, Wih0, 256, 1, (long)GE * 256, b0, GE,
        pre, GE, (long)SEQ * GE, SEQ, GE, 256);
    k_rec_enc<<<2, 512, 0, stream>>>(pre, Whh0, y0, hdec, cdec);

    // pre = y0 @ Wih1^T + b1
    k_gemm<<<dim3(16, 16, 2), 256, 0, stream>>>(
        y0, 512, 0L, Wih1, 512, 1, (long)GE * 512, b1, GE,
        pre, GE, (long)SEQ * GE, SEQ, GE, 512);
    // L1 output overwrites y0 region (y0 is dead after the GEMM above)
    k_rec_enc<<<2, 512, 0, stream>>>(pre, Whh1, y0, hdec + 512, cdec + 512);

    // encK = enc @ Wk
    k_gemm<<<dim3(4, 16, 1), 256, 0, stream>>>(
        y0, 512, 0L, Wk, 1, 256, 0L, nullptr, 0,
        encK, 256, 0L, SEQ, 256, 512);

    // dpre = decin @ dWih[0]^T + db[0]
    k_gemm<<<dim3(32, 1, 1), 256, 0, stream>>>(
        decin, 512, 0L, dWih, 512, 1, 0L, db, 0,
        dpre, GD, 0L, T_STEPS, GD, 512);
    k_rec_dec<<<16, 256, 0, stream>>>(dpre, dWhh, hdec, cdec, h0seq, commD);

    // dpre = h0seq @ dWih[1]^T + db[1]
    k_gemm<<<dim3(32, 1, 1), 256, 0, stream>>>(
        h0seq, 512, 0L, dWih + (long)GD * 512, 512, 1, 0L, db + GD, 0,
        dpre, GD, 0L, T_STEPS, GD, 512);
    k_rec_dec<<<16, 256, 0, stream>>>(dpre, dWhh + (long)GD * 512, hdec + 512, cdec + 512,
                                      h1seq, commD + 32768);

    // q = h1seq @ Wq
    k_gemm<<<dim3(4, 1, 1), 256, 0, stream>>>(
        h1seq, 512, 0L, Wq, 1, 256, 0L, nullptr, 0,
        qseq, 256, 0L, T_STEPS, 256, 512);

    k_attn<<<64, 256, 0, stream>>>(encK, qseq, av, alens, out);
}

// Round 8
// 3980.134 us; speedup vs baseline: 5.9906x; 1.0933x over previous
//
#include <hip/hip_runtime.h>
#include <math.h>

#define T_STEPS 64
#define A_DIM   16
#define SEQ     1024      // T*A
#define HE      256       // encoder hidden per direction
#define DH      512       // decoder hidden
#define GE      1024      // 4*HE
#define GD      2048      // 4*DH

typedef _Float16 h2_t __attribute__((ext_vector_type(2)));

__device__ __forceinline__ float sigf(float x) { return 1.f / (1.f + __expf(-x)); }
// tanh via exp2-based __expf; args here are bounded (|x| < ~4) so no overflow path.
__device__ __forceinline__ float tanh_fast(float x) {
    float e = __expf(-2.f * x);
    return (1.f - e) / (1.f + e);
}

__device__ __forceinline__ float fdot2f(h2_t a, h2_t b, float c) {
#if defined(__has_builtin) && __has_builtin(__builtin_amdgcn_fdot2)
    return __builtin_amdgcn_fdot2(a, b, c, false);
#else
    return c + (float)a.x * (float)b.x + (float)a.y * (float)b.y;
#endif
}

// Agent-scope self-validating comm words. Lessons r1/r2/r7: cross-CU exchange
// must use the L3 coherence point (~900 cy store->load); no faster path
// exists (sc0/L2 reads own-XCD stale lines; single-CU designs hit the
// 128-arch-VGPR cap / RF capacity instead). The r0 8-block polling encoder
// is within ~15% of the structural floor for this recurrence.
__device__ __forceinline__ float poll_comm(const float* p) {
    float v;
    do {
        v = __hip_atomic_load(p, __ATOMIC_RELAXED, __HIP_MEMORY_SCOPE_AGENT);
    } while (v == 0.f);
    return v - 4.0f;
}

__device__ __forceinline__ void post_comm(float* p, float h) {
    __hip_atomic_store(p, h + 4.0f, __ATOMIC_RELAXED, __HIP_MEMORY_SCOPE_AGENT);
}

// ---------------------------------------------------------------------------
// Embedding / decoder-input assembly
// ---------------------------------------------------------------------------
__global__ void k_embed(const int* __restrict__ lattice, const int* __restrict__ inputs,
                        const int* __restrict__ gold, const int* __restrict__ sos,
                        const float* __restrict__ lat_emb, const float* __restrict__ in_emb,
                        float* __restrict__ x, float* __restrict__ decin)
{
    int idx = blockIdx.x * 256 + threadIdx.x;
    if (idx < SEQ * 256) {
        int row = idx >> 8, e = idx & 255;
        int f = e >> 6, eo = e & 63;
        int id = lattice[row * 4 + f];
        x[idx] = lat_emb[id * 64 + eo];
    } else {
        int k = idx - SEQ * 256;
        if (k < T_STEPS * 512) {
            int t = k >> 9, d = k & 511;
            float val;
            if (d < 256) {
                int f = d >> 6, eo = d & 63;
                int id = (t == 0) ? sos[f]
                                  : lattice[(((t - 1) * A_DIM) + gold[t - 1]) * 4 + f];
                val = lat_emb[id * 64 + eo];
            } else {
                val = in_emb[inputs[t] * 256 + (d - 256)];
            }
            decin[k] = val;
        }
    }
}

// ---------------------------------------------------------------------------
// Generic fp32 GEMM: C[m,n] = bias[n] + sum_k A[m*lda+k] * B[n*ldbn + k*ldbk]
// (the two big pre-GEMMs are ~16 us each per arithmetic: 8192 fma/thread;
//  not a bottleneck — left as-is)
// ---------------------------------------------------------------------------
__global__ __launch_bounds__(256) void k_gemm(
    const float* __restrict__ A, int lda, long sA,
    const float* __restrict__ B, int ldbn, int ldbk, long sB,
    const float* __restrict__ bias, int sBias,
    float* __restrict__ C, int ldc, long sC,
    int M, int N, int K)
{
    int b = blockIdx.z;
    A += b * sA; B += b * sB; C += b * sC;
    if (bias) bias += (long)b * sBias;
    int n0 = blockIdx.x * 64, m0 = blockIdx.y * 64;
    __shared__ float As[64][17];
    __shared__ float Bs[64][17];
    int tid = threadIdx.x;
    int tn = tid & 15, tm = tid >> 4;
    float acc[4][4] = {};
    int lk = tid & 15, lr = tid >> 4;
    for (int k0 = 0; k0 < K; k0 += 16) {
#pragma unroll
        for (int i = 0; i < 4; i++) {
            int row = lr + i * 16;
            int am = m0 + row;
            As[row][lk] = (am < M) ? A[(long)am * lda + k0 + lk] : 0.f;
            int bn = n0 + row;
            Bs[row][lk] = (bn < N) ? B[(long)bn * ldbn + (long)(k0 + lk) * ldbk] : 0.f;
        }
        __syncthreads();
#pragma unroll
        for (int k = 0; k < 16; k++) {
            float av[4], bv[4];
#pragma unroll
            for (int i = 0; i < 4; i++) av[i] = As[tm * 4 + i][k];
#pragma unroll
            for (int j = 0; j < 4; j++) bv[j] = Bs[tn * 4 + j][k];
#pragma unroll
            for (int i = 0; i < 4; i++)
#pragma unroll
                for (int j = 0; j < 4; j++) acc[i][j] += av[i] * bv[j];
        }
        __syncthreads();
    }
#pragma unroll
    for (int i = 0; i < 4; i++) {
        int m = m0 + tm * 4 + i;
        if (m >= M) continue;
#pragma unroll
        for (int j = 0; j < 4; j++) {
            int n = n0 + tn * 4 + j;
            if (n < N) C[(long)m * ldc + n] = acc[i][j] + (bias ? bias[n] : 0.f);
        }
    }
}

// ---------------------------------------------------------------------------
// Encoder biLSTM recurrence, one layer. 8 blocks: 0-3 fwd team, 4-7 bwd.
// f16 weights in VGPRs (v_dot2_f32_f16), fp32 accumulate. Cross-block h
// exchange via self-validating comm words (h+4, buffer pre-zeroed): one
// relaxed agent store by the producer, one polled load by the consumer.
// PROVEN r0 version (1508 us/layer) — restored after rounds 1-7 established
// that both the polling latency (~900 cy/step, HW) and all single-CU
// alternatives (128-arch-VGPR cap, RF capacity = weight size, LDS ~100 B/cy)
// bound any encoder design to ~1400-1700 us/layer.
// ---------------------------------------------------------------------------
__global__ __launch_bounds__(256, 1) void k_rec_enc(
    const float* __restrict__ pre,   // [2][SEQ][GE]
    const float* __restrict__ Whh,   // [2][GE][HE]
    float* __restrict__ y,           // [SEQ][512]
    float* __restrict__ hfin,        // [512] this layer's slot
    float* __restrict__ cfin,        // [512]
    float* __restrict__ comm)        // [2][SEQ][HE], zeroed before launch
{
    const int tid = threadIdx.x, bid = blockIdx.x;
    const int r = bid & 3, dir = bid >> 2;
    const bool fwd = (dir == 0);
    const int jj = tid & 63, j = r * 64 + jj;
    const int row = (tid >> 6) * HE + j;          // gate row (i,f,g,o blocks)
    const float* pre_d = pre + (long)dir * SEQ * GE;
    float* comm_d = comm + (long)dir * SEQ * HE;

    h2_t w2[128];
    {
        const float4* wr = (const float4*)(Whh + (long)dir * GE * HE + (long)row * HE);
#pragma unroll
        for (int i = 0; i < 64; i++) {
            float4 v = wr[i];
            w2[2 * i]     = h2_t{(_Float16)v.x, (_Float16)v.y};
            w2[2 * i + 1] = h2_t{(_Float16)v.z, (_Float16)v.w};
        }
    }

    __shared__ __align__(16) _Float16 hsArr[HE];
    __shared__ float gl[256];
    hsArr[tid] = (_Float16)0.f;
    __syncthreads();

    float c = 0.f, h_cur = 0.f;
    float pre_cur = pre_d[(long)(fwd ? 0 : SEQ - 1) * GE + row];

    for (int s = 0; s < SEQ; s++) {
        const int t = fwd ? s : SEQ - 1 - s;
        float acc = 0.f;
        const float4* hv = (const float4*)hsArr;
#pragma unroll
        for (int kk = 0; kk < 32; kk++) {
            float4 blk = hv[kk];
            const h2_t* hp = (const h2_t*)&blk;
            acc = fdot2f(w2[4 * kk + 0], hp[0], acc);
            acc = fdot2f(w2[4 * kk + 1], hp[1], acc);
            acc = fdot2f(w2[4 * kk + 2], hp[2], acc);
            acc = fdot2f(w2[4 * kk + 3], hp[3], acc);
        }
        gl[tid] = pre_cur + acc;
        if (s + 1 < SEQ) pre_cur = pre_d[(long)(fwd ? t + 1 : t - 1) * GE + row];
        __syncthreads();
        if (tid < 64) {
            float gi = gl[jj], gf = gl[64 + jj], gg = gl[128 + jj], go = gl[192 + jj];
            c = sigf(gf) * c + sigf(gi) * tanh_fast(gg);
            h_cur = sigf(go) * tanh_fast(c);
            post_comm(&comm_d[(long)t * HE + j], h_cur);   // publish FIRST
            y[(long)t * 512 + dir * HE + j] = h_cur;
            hsArr[j] = (_Float16)h_cur;                    // own slice direct
        }
        if (s + 1 < SEQ && tid < 192) {                    // fetch 192 remote
            int idx = (r * 64 + 64 + tid) & 255;
            hsArr[idx] = (_Float16)poll_comm(&comm_d[(long)t * HE + idx]);
        }
        __syncthreads();
    }
    if (tid < 64) {
        hfin[dir * HE + j] = h_cur;
        cfin[dir * HE + j] = c;
    }
}

// ---------------------------------------------------------------------------
// Decoder LSTM recurrence, one layer. 16 blocks; block r owns h[r*32..+32).
// Row K=512 split across thread pairs (256 f16 weights each).
// CHANGE vs r0: the two sequential remote-poll loops (two serialized ~900-cy
// L3 round trips per step) are merged into ONE dual-issue spin — both loads
// are in flight before either is checked, halving the propagation term.
// Returned data and all arithmetic are identical to r0.
// ---------------------------------------------------------------------------
__global__ __launch_bounds__(256, 1) void k_rec_dec(
    const float* __restrict__ pre,    // [64][GD]
    const float* __restrict__ Whh,    // [GD][DH] (layer-selected)
    const float* __restrict__ hinit,  // [512]
    const float* __restrict__ cinit,  // [512]
    float* __restrict__ hseq,         // [64][512]
    float* __restrict__ comm)         // [64][512], zeroed before launch
{
    const int tid = threadIdx.x, r = blockIdx.x;
    const int kh = tid >> 7, rem = tid & 127;
    const int q = rem >> 5, jj = rem & 31;
    const int row = q * DH + r * 32 + jj;
    const int k0 = kh * 256;

    h2_t w2[128];
    {
        const float4* wr = (const float4*)(Whh + (long)row * DH + k0);
#pragma unroll
        for (int i = 0; i < 64; i++) {
            float4 v = wr[i];
            w2[2 * i]     = h2_t{(_Float16)v.x, (_Float16)v.y};
            w2[2 * i + 1] = h2_t{(_Float16)v.z, (_Float16)v.w};
        }
    }

    __shared__ __align__(16) _Float16 hsArr[DH];
    __shared__ float part[256];
    __shared__ float gate[128];
    hsArr[tid] = (_Float16)hinit[tid];
    hsArr[tid + 256] = (_Float16)hinit[tid + 256];
    float c = (tid < 32) ? cinit[r * 32 + tid] : 0.f;
    float pre_cur = (tid < 128) ? pre[row] : 0.f;
    float h_cur = 0.f;
    __syncthreads();

    for (int s = 0; s < T_STEPS; s++) {
        float acc = 0.f;
        const float4* hv = (const float4*)(hsArr + k0);
#pragma unroll
        for (int kk = 0; kk < 32; kk++) {
            float4 blk = hv[kk];
            const h2_t* hp = (const h2_t*)&blk;
            acc = fdot2f(w2[4 * kk + 0], hp[0], acc);
            acc = fdot2f(w2[4 * kk + 1], hp[1], acc);
            acc = fdot2f(w2[4 * kk + 2], hp[2], acc);
            acc = fdot2f(w2[4 * kk + 3], hp[3], acc);
        }
        part[tid] = acc;
        __syncthreads();
        if (tid < 128) {
            float g = part[tid] + part[tid + 128] + pre_cur;
            if (s + 1 < T_STEPS) pre_cur = pre[(long)(s + 1) * GD + row];
            gate[tid] = g;
        }
        __syncthreads();
        if (tid < 32) {
            int jg = r * 32 + tid;
            float gi = gate[tid], gf = gate[32 + tid], gg = gate[64 + tid], go = gate[96 + tid];
            c = sigf(gf) * c + sigf(gi) * tanh_fast(gg);
            h_cur = sigf(go) * tanh_fast(c);
            post_comm(&comm[(long)s * DH + jg], h_cur);
            hseq[(long)s * DH + jg] = h_cur;
            hsArr[jg] = (_Float16)h_cur;
        }
        if (s + 1 < T_STEPS) {
            const float* cs = &comm[(long)s * DH];
            int idx2 = (r * 32 + 256 + tid) & 511;         // rel 256..511 (all)
            if (tid < 224) {
                int idx1 = (r * 32 + 32 + tid) & 511;      // rel 32..255
                float v1, v2;
                bool d1 = false, d2 = false;
                do {
                    if (!d1) {
                        v1 = __hip_atomic_load(&cs[idx1], __ATOMIC_RELAXED,
                                               __HIP_MEMORY_SCOPE_AGENT);
                        d1 = (v1 != 0.f);
                    }
                    if (!d2) {
                        v2 = __hip_atomic_load(&cs[idx2], __ATOMIC_RELAXED,
                                               __HIP_MEMORY_SCOPE_AGENT);
                        d2 = (v2 != 0.f);
                    }
                } while (!(d1 && d2));
                hsArr[idx1] = (_Float16)(v1 - 4.0f);
                hsArr[idx2] = (_Float16)(v2 - 4.0f);
            } else {
                hsArr[idx2] = (_Float16)poll_comm(&cs[idx2]);
            }
        }
        __syncthreads();
    }
}

// ---------------------------------------------------------------------------
// Attention readout
// ---------------------------------------------------------------------------
__global__ void k_attn(const float* __restrict__ encK, const float* __restrict__ qs,
                       const float* __restrict__ v, const int* __restrict__ alens,
                       float* __restrict__ out)
{
    int t = blockIdx.x;
    int tid = threadIdx.x;
    int wave = tid >> 6, lane = tid & 63;
    int len = alens[t];
    const float* qt = qs + t * 256;
    for (int a = wave; a < A_DIM; a += 4) {
        const float* ek = encK + (long)(t * A_DIM + a) * 256;
        float sum = 0.f;
#pragma unroll
        for (int e = 0; e < 4; e++) {
            int d = lane * 4 + e;
            sum += v[d] * tanhf(ek[d] + qt[d]);
        }
        for (int off = 32; off; off >>= 1) sum += __shfl_down(sum, off, 64);
        if (lane == 0) out[t * A_DIM + a] = (a < len) ? sum : -1e10f;
    }
}

// ---------------------------------------------------------------------------
extern "C" void kernel_launch(void* const* d_in, const int* in_sizes, int n_in,
                              void* d_out, int out_size, void* d_ws, size_t ws_size,
                              hipStream_t stream)
{
    (void)in_sizes; (void)n_in; (void)out_size; (void)ws_size;
    const int*   lattice = (const int*)d_in[0];
    const int*   alens   = (const int*)d_in[1];
    const int*   inputs  = (const int*)d_in[2];
    const int*   gold    = (const int*)d_in[4];
    const int*   sos     = (const int*)d_in[5];
    const float* lat_emb = (const float*)d_in[6];
    const float* in_emb  = (const float*)d_in[7];
    const float* Wih0    = (const float*)d_in[8];
    const float* Whh0    = (const float*)d_in[9];
    const float* b0      = (const float*)d_in[10];
    const float* Wih1    = (const float*)d_in[11];
    const float* Whh1    = (const float*)d_in[12];
    const float* b1      = (const float*)d_in[13];
    const float* dWih    = (const float*)d_in[14];
    const float* dWhh    = (const float*)d_in[15];
    const float* db      = (const float*)d_in[16];
    const float* Wq      = (const float*)d_in[17];
    const float* Wk      = (const float*)d_in[18];
    const float* av      = (const float*)d_in[19];
    float* out = (float*)d_out;
    float* ws  = (float*)d_ws;

    // ws layout (floats) — total 3,770,368 floats = 15.08 MB (≤15.7 MB proven)
    float* comm  = ws;                  // 524288  [2][1024][256], reused per enc layer
    float* commD = ws + 524288;         // 65536   [2 layers][64][512]
    float* xbuf  = ws + 589824;         // 262144  x; later decoder scratch:
    float* dpre  = xbuf;                //   131072
    float* h0seq = xbuf + 131072;       //   32768
    float* h1seq = xbuf + 163840;       //   32768
    float* qseq  = xbuf + 196608;       //   16384
    float* pre   = ws + 851968;         // 2097152 (per-layer gate pre-activations)
    float* y0    = ws + 2949120;        // 524288  L0 output; reused as enc (L1 out)
    float* hdec  = ws + 3473408;        // 1024    [2][512]
    float* cdec  = ws + 3474432;        // 1024
    float* decin = ws + 3475456;        // 32768   [64][512]
    float* encK  = ws + 3508224;        // 262144

    // zero comm + commD (poisoned 0xAA before every launch)
    hipMemsetAsync(ws, 0, (524288 + 65536) * sizeof(float), stream);

    k_embed<<<1152, 256, 0, stream>>>(lattice, inputs, gold, sos, lat_emb, in_emb, xbuf, decin);

    // pre = x @ Wih0^T + b0  (both dirs)
    k_gemm<<<dim3(16, 16, 2), 256, 0, stream>>>(
        xbuf, 256, 0L, Wih0, 256, 1, (long)GE * 256, b0, GE,
        pre, GE, (long)SEQ * GE, SEQ, GE, 256);
    k_rec_enc<<<8, 256, 0, stream>>>(pre, Whh0, y0, hdec, cdec, comm);

    // re-zero comm for layer 1
    hipMemsetAsync(comm, 0, 524288 * sizeof(float), stream);

    // pre = y0 @ Wih1^T + b1
    k_gemm<<<dim3(16, 16, 2), 256, 0, stream>>>(
        y0, 512, 0L, Wih1, 512, 1, (long)GE * 512, b1, GE,
        pre, GE, (long)SEQ * GE, SEQ, GE, 512);
    // L1 output overwrites y0 region (y0 is dead after the GEMM above)
    k_rec_enc<<<8, 256, 0, stream>>>(pre, Whh1, y0, hdec + 512, cdec + 512, comm);

    // encK = enc @ Wk
    k_gemm<<<dim3(4, 16, 1), 256, 0, stream>>>(
        y0, 512, 0L, Wk, 1, 256, 0L, nullptr, 0,
        encK, 256, 0L, SEQ, 256, 512);

    // dpre = decin @ dWih[0]^T + db[0]
    k_gemm<<<dim3(32, 1, 1), 256, 0, stream>>>(
        decin, 512, 0L, dWih, 512, 1, 0L, db, 0,
        dpre, GD, 0L, T_STEPS, GD, 512);
    k_rec_dec<<<16, 256, 0, stream>>>(dpre, dWhh, hdec, cdec, h0seq, commD);

    // dpre = h0seq @ dWih[1]^T + db[1]
    k_gemm<<<dim3(32, 1, 1), 256, 0, stream>>>(
        h0seq, 512, 0L, dWih + (long)GD * 512, 512, 1, 0L, db + GD, 0,
        dpre, GD, 0L, T_STEPS, GD, 512);
    k_rec_dec<<<16, 256, 0, stream>>>(dpre, dWhh + (long)GD * 512, hdec + 512, cdec + 512,
                                      h1seq, commD + 32768);

    // q = h1seq @ Wq
    k_gemm<<<dim3(4, 1, 1), 256, 0, stream>>>(
        h1seq, 512, 0L, Wq, 1, 256, 0L, nullptr, 0,
        qseq, 256, 0L, T_STEPS, 256, 512);

    k_attn<<<64, 256, 0, stream>>>(encK, qseq, av, alens, out);
}